// Round 7
// baseline (299.206 us; speedup 1.0000x reference)
//
#include <hip/hip_runtime.h>
#include <hip/hip_bf16.h>

#define NUM_CLASSES 100000
#define DIM 256
#define BATCH 256
#define NUM_TRUE 1024
#define NUM_SAMPLED 16384
// ln(NUM_CLASSES + 1)
#define LOG_RANGE 11.51293546492023f
#define INV_LOG_RANGE (1.0f / LOG_RANGE)

#define SBLOCKS 512   // sampled blocks (32 s-rows each), scheduled first
#define WBLOCKS 512   // sweep blocks for the true part
#define CPB 196       // classes per sweep block (512*196 = 100352 >= 100000)
#define CPW 49        // classes per wave (4 waves/block)
#define CAP 32        // bucket capacity per class (Poisson mean 2.62; P(>32) ~ 0)

typedef __bf16 bf16x8 __attribute__((ext_vector_type(8)));
typedef float  f32x4  __attribute__((ext_vector_type(4)));

// RNE float -> bf16 bits
static __device__ __forceinline__ unsigned short f2bf(float f) {
    unsigned int u = __float_as_uint(f);
    unsigned int lsb = (u >> 16) & 1u;
    u += 0x7fffu + lsb;
    return (unsigned short)(u >> 16);
}

// -log(expected_count(id)) inline, fast-math formulation (validated r6: absmax 0.0)
static __device__ __forceinline__ float neg_log_ec_fast(int id) {
    float idf = (float)id;
    float e = 1.0f / (idf + 1.0f);
    float p = log1pf(e) * INV_LOG_RANGE;
    float q = p * (1.0f + 0.5f * p + 0.3333333f * p * p);
    float ec = 1.0f - __expf(-(float)NUM_SAMPLED * q);
    return -__logf(ec);
}

static __device__ __forceinline__ float dot4(float4 a, float4 b) {
    return fmaf(a.x, b.x, fmaf(a.y, b.y, fmaf(a.z, b.z, a.w * b.w)));
}

// ---- scatter: per-class bucket of batch ids; also inputs fp32 -> bf16 ----
__global__ __launch_bounds__(256) void scatter_kernel(const int* __restrict__ labels,
                                                      const float* __restrict__ inputs,
                                                      int* __restrict__ counts,
                                                      unsigned char* __restrict__ bucket,
                                                      unsigned short* __restrict__ inbf) {
    const int gid = blockIdx.x * 256 + threadIdx.x;   // 262144 threads
    const int c = labels[gid];
    const int b = gid >> 10;                          // labels are [b][t] flat
    int pos = atomicAdd(&counts[c], 1);
    if (pos < CAP) bucket[c * CAP + pos] = (unsigned char)b;
    if (gid < (BATCH * DIM) / 4) {                    // 16384 float4s
        float4 v = ((const float4*)inputs)[gid];
        ushort4 p;
        p.x = f2bf(v.x); p.y = f2bf(v.y); p.z = f2bf(v.z); p.w = f2bf(v.w);
        ((ushort4*)inbf)[gid] = p;
    }
}

// ---------------- fused: sampled gather blocks first, then true SWEEP ----------
__global__ __launch_bounds__(256) void fused_kernel(const float* __restrict__ inputs,
                                                    const float* __restrict__ w,
                                                    const float* __restrict__ bias,
                                                    const int* __restrict__ sampled,
                                                    const int* __restrict__ counts,
                                                    const unsigned char* __restrict__ bucket,
                                                    const unsigned short* __restrict__ inbf,
                                                    float* __restrict__ partialS,
                                                    float* __restrict__ partialT) {
    __shared__ unsigned short lw[32][264];   // sampled w tile, bf16 (16.9 KB)
    __shared__ float cs[32];
    __shared__ float bacc[BATCH];

    const int tid = threadIdx.x;

    if (blockIdx.x < SBLOCKS) {
        // ================= sampled path: 32 s-rows x 256 batch =================
        const int sblk = blockIdx.x;
        const int s0 = sblk * 32;
        bacc[tid] = 0.0f;

        const int inner = tid & 15;
        const int r16   = tid >> 4;
        #pragma unroll
        for (int rb = 0; rb < 2; ++rb) {
            const int r = rb * 16 + r16;
            const int id = sampled[s0 + r];
            const float* src = w + (size_t)id * DIM;
            #pragma unroll
            for (int j = 0; j < 4; ++j) {
                float4 v = *(const float4*)(src + j * 64 + inner * 4);
                ushort4 pk;
                pk.x = f2bf(v.x); pk.y = f2bf(v.y); pk.z = f2bf(v.z); pk.w = f2bf(v.w);
                *(ushort4*)(&lw[r][j * 64 + inner * 4]) = pk;
            }
        }
        if (tid < 32) {
            const int id = sampled[s0 + tid];
            cs[tid] = bias[id] + neg_log_ec_fast(id);
        }
        __syncthreads();

        const int lane = tid & 63;
        const int wv   = tid >> 6;
        const int m    = lane & 15;
        const int quad = lane >> 4;
        const int shalf = (wv >> 1) * 16;
        const int bhalf = (wv & 1) * 128;

        bf16x8 af[8];
        #pragma unroll
        for (int kk = 0; kk < 8; ++kk)
            af[kk] = *(const bf16x8*)(&lw[shalf + m][kk * 32 + quad * 8]);

        #pragma unroll
        for (int t = 0; t < 8; ++t) {
            const int brow = bhalf + t * 16 + m;
            const unsigned short* bp = inbf + brow * DIM;
            bf16x8 bf[8];
            #pragma unroll
            for (int kk = 0; kk < 8; ++kk)
                bf[kk] = *(const bf16x8*)(bp + kk * 32 + quad * 8);
            f32x4 acc = {0, 0, 0, 0};
            #pragma unroll
            for (int kk = 0; kk < 8; ++kk)
                acc = __builtin_amdgcn_mfma_f32_16x16x32_bf16(af[kk], bf[kk], acc, 0, 0, 0);
            float ps = 0.0f;
            #pragma unroll
            for (int r = 0; r < 4; ++r) {
                float c = cs[shalf + quad * 4 + r];
                float l = acc[r] + c;
                ps += fmaxf(l, 0.0f) + __logf(1.0f + __expf(-fabsf(l)));
            }
            ps += __shfl_xor(ps, 16); ps += __shfl_xor(ps, 32);
            if (quad == 0) atomicAdd(&bacc[bhalf + t * 16 + m], ps);
        }
        __syncthreads();
        partialS[tid * SBLOCKS + sblk] = bacc[tid];   // [b][sblk]
    } else {
        // ========== true path: sequential class sweep, depth-2 row prefetch =====
        const int swblk = blockIdx.x - SBLOCKS;
        bacc[tid] = 0.0f;
        __syncthreads();

        const int lane = tid & 63;
        const int wv   = tid >> 6;
        const int c0   = swblk * CPB + wv * CPW;

        float4 row[2]; int cnt[2]; float bs[2]; int be[2];
        #pragma unroll
        for (int s = 0; s < 2; ++s) {
            const int c = c0 + s;
            const int cc = (c < NUM_CLASSES) ? c : (NUM_CLASSES - 1);
            row[s] = ((const float4*)(w + (size_t)cc * DIM))[lane];
            cnt[s] = (c < NUM_CLASSES) ? counts[cc] : 0;
            bs[s]  = bias[cc];
            be[s]  = bucket[cc * CAP + (lane & 31)];   // whole bucket row, 32 B
        }

        for (int i = 0; i < CPW; ++i) {
            const int cur = i & 1;
            const float4 wr = row[cur];
            int n = cnt[cur];
            const float bv = bs[cur];
            const int bent = be[cur];
            const int c = c0 + i;
            if (i + 2 < CPW) {    // refill two classes ahead
                const int c2 = c0 + i + 2;
                const int cc = (c2 < NUM_CLASSES) ? c2 : (NUM_CLASSES - 1);
                row[cur] = ((const float4*)(w + (size_t)cc * DIM))[lane];
                cnt[cur] = (c2 < NUM_CLASSES) ? counts[cc] : 0;
                bs[cur]  = bias[cc];
                be[cur]  = bucket[cc * CAP + (lane & 31)];
            }
            if (n > 0) {
                if (n > CAP) n = CAP;
                const float cl = bv + neg_log_ec_fast(c);
                int b0 = __shfl(bent, 0);
                float4 iv = ((const float4*)(inputs + b0 * DIM))[lane];
                for (int j = 0; j < n; ++j) {
                    const int bb = __shfl(bent, j);
                    float4 ivn = {0, 0, 0, 0};
                    if (j + 1 < n) {
                        const int bn = __shfl(bent, j + 1);
                        ivn = ((const float4*)(inputs + bn * DIM))[lane];
                    }
                    float d = dot4(wr, iv);
                    d += __shfl_xor(d, 1);  d += __shfl_xor(d, 2);
                    d += __shfl_xor(d, 4);  d += __shfl_xor(d, 8);
                    d += __shfl_xor(d, 16); d += __shfl_xor(d, 32);
                    const float logit = d + cl;
                    const float v = fmaxf(logit, 0.0f) - logit * (1.0f / (float)NUM_TRUE)
                                  + __logf(1.0f + __expf(-fabsf(logit)));
                    if (lane == 0) atomicAdd(&bacc[bb], v);
                    iv = ivn;
                }
            }
        }
        __syncthreads();
        partialT[tid * WBLOCKS + swblk] = bacc[tid];   // [b][swblk]
    }
}

// ---- final reduce: out[b] = sum of 512 sampled + 512 sweep partials ----
__global__ __launch_bounds__(256) void reduce_kernel(const float* __restrict__ partialS,
                                                     const float* __restrict__ partialT,
                                                     float* __restrict__ out) {
    __shared__ float wsum[4];
    const int b = blockIdx.x;
    const int tid = threadIdx.x;
    float v = partialS[b * SBLOCKS + tid] + partialS[b * SBLOCKS + 256 + tid]
            + partialT[b * WBLOCKS + tid] + partialT[b * WBLOCKS + 256 + tid];
    v += __shfl_xor(v, 1);  v += __shfl_xor(v, 2);  v += __shfl_xor(v, 4);
    v += __shfl_xor(v, 8);  v += __shfl_xor(v, 16); v += __shfl_xor(v, 32);
    if ((tid & 63) == 0) wsum[tid >> 6] = v;
    __syncthreads();
    if (tid == 0) out[b] = wsum[0] + wsum[1] + wsum[2] + wsum[3];
}

extern "C" void kernel_launch(void* const* d_in, const int* in_sizes, int n_in,
                              void* d_out, int out_size, void* d_ws, size_t ws_size,
                              hipStream_t stream) {
    const float* inputs  = (const float*)d_in[0];   // [256,256]
    const float* w       = (const float*)d_in[1];   // [100000,256]
    const float* bias    = (const float*)d_in[2];   // [100000]
    const int*   labels  = (const int*)d_in[3];     // [256,1024]
    const int*   sampled = (const int*)d_in[4];     // [16384]
    float* out = (float*)d_out;                     // [256]

    int*            counts   = (int*)d_ws;                                  // 400 KB
    unsigned char*  bucket   = (unsigned char*)d_ws + 409600;               // 3.2 MB
    unsigned short* inbf     = (unsigned short*)((char*)d_ws + 3612672);    // 128 KB
    float*          partialS = (float*)((char*)d_ws + 3743744);             // 512 KB
    float*          partialT = (float*)((char*)d_ws + 4268032);             // 512 KB

    hipMemsetAsync(counts, 0, NUM_CLASSES * sizeof(int), stream);
    scatter_kernel<<<(BATCH * NUM_TRUE) / 256, 256, 0, stream>>>(labels, inputs,
                                                                 counts, bucket, inbf);
    fused_kernel<<<SBLOCKS + WBLOCKS, 256, 0, stream>>>(inputs, w, bias, sampled,
                                                        counts, bucket, inbf,
                                                        partialS, partialT);
    reduce_kernel<<<BATCH, 256, 0, stream>>>(partialS, partialT, out);
}

// Round 8
// 236.779 us; speedup vs baseline: 1.2637x; 1.2637x over previous
//
#include <hip/hip_runtime.h>
#include <hip/hip_bf16.h>

#define NUM_CLASSES 100000
#define CLS_PAD 102400            // 1600 sweep blocks * 64 classes
#define DIM 256
#define BATCH 256
#define NUM_TRUE 1024
#define NUM_SAMPLED 16384
// ln(NUM_CLASSES + 1)
#define LOG_RANGE 11.51293546492023f
#define INV_LOG_RANGE (1.0f / LOG_RANGE)
#define SWEEP_BLOCKS 1600

typedef __bf16 bf16x8 __attribute__((ext_vector_type(8)));
typedef float  f32x4  __attribute__((ext_vector_type(4)));
typedef unsigned short us8 __attribute__((ext_vector_type(8)));

// RNE float -> bf16 bits
static __device__ __forceinline__ unsigned short f2bf(float f) {
    unsigned int u = __float_as_uint(f);
    unsigned int lsb = (u >> 16) & 1u;
    u += 0x7fffu + lsb;
    return (unsigned short)(u >> 16);
}

// -log(expected_count(id)) inline, fast-math formulation (validated r6/r7: absmax 0.0)
static __device__ __forceinline__ float neg_log_ec_fast(int id) {
    float idf = (float)id;
    float e = 1.0f / (idf + 1.0f);
    float p = log1pf(e) * INV_LOG_RANGE;
    float q = p * (1.0f + 0.5f * p + 0.3333333f * p * p);
    float ec = 1.0f - __expf(-(float)NUM_SAMPLED * q);
    return -__logf(ec);
}

// ---- scatter: 4-bit multiplicity table[c][b], sampled flags, inputs->bf16 ----
__global__ __launch_bounds__(256) void scatter_kernel(const int* __restrict__ labels,
                                                      const int* __restrict__ sampled,
                                                      const float* __restrict__ inputs,
                                                      unsigned int* __restrict__ table,
                                                      unsigned char* __restrict__ flags,
                                                      unsigned short* __restrict__ inbf) {
    const int gid = blockIdx.x * 256 + threadIdx.x;   // 262144 threads
    const int c = labels[gid];
    const int b = gid >> 10;                          // labels are [b][t] flat
    atomicAdd(&table[c * 32 + (b >> 3)], 1u << ((b & 7) * 4));
    if (gid < NUM_SAMPLED) flags[sampled[gid]] = 1;   // sampled ids unique
    if (gid < (BATCH * DIM) / 4) {
        float4 v = ((const float4*)inputs)[gid];
        ushort4 p;
        p.x = f2bf(v.x); p.y = f2bf(v.y); p.z = f2bf(v.z); p.w = f2bf(v.w);
        ((ushort4*)inbf)[gid] = p;
    }
}

// ---- sweep: full [100k x 256] logit GEMM, epilogue resolves true+sampled xent ----
// 1600 blocks x 128 threads; block = 64 consecutive classes x 256 batch.
// w rows streamed ONCE from HBM (sequential); B-frags from L2-hot bf16 inputs.
__global__ __launch_bounds__(128) void sweep_kernel(const float* __restrict__ w,
                                                    const float* __restrict__ bias,
                                                    const unsigned int* __restrict__ table,
                                                    const unsigned char* __restrict__ flags,
                                                    const unsigned short* __restrict__ inbf,
                                                    float* __restrict__ partial) {
    __shared__ unsigned int lmask[64][32];   // 4-bit counts, 64 classes x 256 b (8 KB)
    __shared__ float cs[64];                 // bias[c] - log(ec(c))
    __shared__ float sf[64];                 // 1.0 if c in sampled set
    __shared__ float bacc[BATCH];

    const int tid = threadIdx.x;
    const int c0  = blockIdx.x * 64;

    // stage masks: 2048 words by 128 threads (coalesced int4)
    {
        const int4* src = (const int4*)(table + (size_t)c0 * 32);
        int4* dst = (int4*)&lmask[0][0];
        #pragma unroll
        for (int j = 0; j < 4; ++j) dst[j * 128 + tid] = src[j * 128 + tid];
    }
    if (tid < 64) {
        const int c = c0 + tid;
        const int cc = (c < NUM_CLASSES) ? c : (NUM_CLASSES - 1);
        cs[tid] = bias[cc] + neg_log_ec_fast(c);
        sf[tid] = flags[c] ? 1.0f : 0.0f;    // padded classes: table=0,flag=0 -> no-op
    }
    bacc[tid] = 0.0f; bacc[tid + 128] = 0.0f;

    const int lane = tid & 63;
    const int wv   = tid >> 6;
    const int m    = lane & 15;
    const int quad = lane >> 4;

    // A-fragments: this wave's 32 classes, direct from global fp32 w (streamed)
    bf16x8 af[2][8];
    #pragma unroll
    for (int s = 0; s < 2; ++s) {
        int c = c0 + wv * 32 + s * 16 + m;
        if (c >= NUM_CLASSES) c = NUM_CLASSES - 1;   // clamp: masked to 0 in epilogue
        const float* wr = w + (size_t)c * DIM + quad * 8;
        #pragma unroll
        for (int kk = 0; kk < 8; ++kk) {
            float4 v0 = *(const float4*)(wr + kk * 32);
            float4 v1 = *(const float4*)(wr + kk * 32 + 4);
            union { us8 u; bf16x8 b; } t;
            t.u[0] = f2bf(v0.x); t.u[1] = f2bf(v0.y); t.u[2] = f2bf(v0.z); t.u[3] = f2bf(v0.w);
            t.u[4] = f2bf(v1.x); t.u[5] = f2bf(v1.y); t.u[6] = f2bf(v1.z); t.u[7] = f2bf(v1.w);
            af[s][kk] = t.b;
        }
    }
    __syncthreads();

    const int cbase = wv * 32;
    for (int t = 0; t < 16; ++t) {
        const unsigned short* bp = inbf + (t * 16 + m) * DIM + quad * 8;
        bf16x8 bf[8];
        #pragma unroll
        for (int kk = 0; kk < 8; ++kk) bf[kk] = *(const bf16x8*)(bp + kk * 32);
        f32x4 a0 = {0, 0, 0, 0}, a1 = {0, 0, 0, 0};
        #pragma unroll
        for (int kk = 0; kk < 8; ++kk) {
            a0 = __builtin_amdgcn_mfma_f32_16x16x32_bf16(af[0][kk], bf[kk], a0, 0, 0, 0);
            a1 = __builtin_amdgcn_mfma_f32_16x16x32_bf16(af[1][kk], bf[kk], a1, 0, 0, 0);
        }
        // epilogue: C/D row(class)=quad*4+r, col(batch)=m  (r6-verified mapping)
        const int wofs = t * 2 + (m >> 3);
        const int nsh  = (m & 7) * 4;
        float ps = 0.0f;
        #pragma unroll
        for (int r = 0; r < 4; ++r) {
            {
                const int cl = cbase + quad * 4 + r;
                float l = a0[r] + cs[cl];
                float kf = (float)((lmask[cl][wofs] >> nsh) & 15u);
                float base = fmaxf(l, 0.0f) + __logf(1.0f + __expf(-fabsf(l)));
                ps += (kf + sf[cl]) * base - kf * l * (1.0f / (float)NUM_TRUE);
            }
            {
                const int cl = cbase + 16 + quad * 4 + r;
                float l = a1[r] + cs[cl];
                float kf = (float)((lmask[cl][wofs] >> nsh) & 15u);
                float base = fmaxf(l, 0.0f) + __logf(1.0f + __expf(-fabsf(l)));
                ps += (kf + sf[cl]) * base - kf * l * (1.0f / (float)NUM_TRUE);
            }
        }
        ps += __shfl_xor(ps, 16); ps += __shfl_xor(ps, 32);   // sum the 4 quads
        if (quad == 0) atomicAdd(&bacc[t * 16 + m], ps);
    }
    __syncthreads();
    partial[blockIdx.x * BATCH + tid]       = bacc[tid];
    partial[blockIdx.x * BATCH + 128 + tid] = bacc[128 + tid];
}

// ---- final reduce: out[b] = sum over 1600 block partials ----
__global__ __launch_bounds__(256) void reduce_kernel(const float* __restrict__ partial,
                                                     float* __restrict__ out) {
    __shared__ float wsum[4];
    const int b = blockIdx.x;
    const int tid = threadIdx.x;
    float v = 0.0f;
    #pragma unroll
    for (int j = 0; j < 6; ++j) v += partial[(j * 256 + tid) * BATCH + b];
    if (tid < SWEEP_BLOCKS - 1536) v += partial[(1536 + tid) * BATCH + b];
    v += __shfl_xor(v, 1);  v += __shfl_xor(v, 2);  v += __shfl_xor(v, 4);
    v += __shfl_xor(v, 8);  v += __shfl_xor(v, 16); v += __shfl_xor(v, 32);
    if ((tid & 63) == 0) wsum[tid >> 6] = v;
    __syncthreads();
    if (tid == 0) out[b] = wsum[0] + wsum[1] + wsum[2] + wsum[3];
}

extern "C" void kernel_launch(void* const* d_in, const int* in_sizes, int n_in,
                              void* d_out, int out_size, void* d_ws, size_t ws_size,
                              hipStream_t stream) {
    const float* inputs  = (const float*)d_in[0];   // [256,256]
    const float* w       = (const float*)d_in[1];   // [100000,256]
    const float* bias    = (const float*)d_in[2];   // [100000]
    const int*   labels  = (const int*)d_in[3];     // [256,1024]
    const int*   sampled = (const int*)d_in[4];     // [16384]
    float* out = (float*)d_out;                     // [256]

    unsigned int*   table   = (unsigned int*)d_ws;                            // 13,107,200 B
    unsigned char*  flags   = (unsigned char*)d_ws + 13107200;                // 102,400 B
    unsigned short* inbf    = (unsigned short*)((char*)d_ws + 13209600);      // 131,072 B
    float*          partial = (float*)((char*)d_ws + 13340672);               // 1,638,400 B

    hipMemsetAsync(table, 0, 13209600, stream);     // table + flags
    scatter_kernel<<<(BATCH * NUM_TRUE) / 256, 256, 0, stream>>>(labels, sampled, inputs,
                                                                 table, flags, inbf);
    sweep_kernel<<<SWEEP_BLOCKS, 128, 0, stream>>>(w, bias, table, flags, inbf, partial);
    reduce_kernel<<<BATCH, 256, 0, stream>>>(partial, out);
}

// Round 9
// 209.352 us; speedup vs baseline: 1.4292x; 1.1310x over previous
//
#include <hip/hip_runtime.h>
#include <hip/hip_bf16.h>

#define NUM_CLASSES 100000
#define DIM 256
#define BATCH 256
#define NUM_TRUE 1024
#define NUM_SAMPLED 16384
// ln(NUM_CLASSES + 1)
#define LOG_RANGE 11.51293546492023f
#define INV_LOG_RANGE (1.0f / LOG_RANGE)

#define SWEEP_BLOCKS 1563          // 1563 * 64 = 100032 classes (32 padded)
#define CLS_PAD 100032

typedef __bf16 bf16x8 __attribute__((ext_vector_type(8)));
typedef float  f32x4  __attribute__((ext_vector_type(4)));

// RNE float -> bf16 bits
static __device__ __forceinline__ unsigned short f2bf(float f) {
    unsigned int u = __float_as_uint(f);
    unsigned int lsb = (u >> 16) & 1u;
    u += 0x7fffu + lsb;
    return (unsigned short)(u >> 16);
}

// -log(expected_count(id)), fast-math (validated r6-r8: absmax 0.0)
static __device__ __forceinline__ float neg_log_ec_fast(int id) {
    float idf = (float)id;
    float e = 1.0f / (idf + 1.0f);
    float p = log1pf(e) * INV_LOG_RANGE;
    float q = p * (1.0f + 0.5f * p + 0.3333333f * p * p);
    float ec = 1.0f - __expf(-(float)NUM_SAMPLED * q);
    return -__logf(ec);
}

// ---- scatter: 4-bit multiplicity table[c][b], sampled flags, inputs->bf16 ----
__global__ __launch_bounds__(256) void scatter_kernel(const int* __restrict__ labels,
                                                      const int* __restrict__ sampled,
                                                      const float* __restrict__ inputs,
                                                      unsigned int* __restrict__ table,
                                                      unsigned char* __restrict__ flags,
                                                      unsigned short* __restrict__ inbf) {
    const int gid = blockIdx.x * 256 + threadIdx.x;   // 262144 threads
    const int c = labels[gid];
    const int b = gid >> 10;                          // labels are [b][t] flat
    atomicAdd(&table[c * 32 + (b >> 3)], 1u << ((b & 7) * 4));
    if (gid < NUM_SAMPLED) {
        flags[sampled[gid]] = 1;                      // sampled ids unique
        float4 v = ((const float4*)inputs)[gid];      // 16384 float4s = all inputs
        ushort4 p;
        p.x = f2bf(v.x); p.y = f2bf(v.y); p.z = f2bf(v.z); p.w = f2bf(v.w);
        ((ushort4*)inbf)[gid] = p;
    }
}

// ---- sweep: full [100k x 256] logit GEMM; epilogue resolves true+sampled xent ----
// 1563 blocks x 256 threads; block = 64 classes (2 phases of 32) x 256 batch.
// A staged coalesced (1 KB contiguous per wave-instr) -> bf16 LDS; B depth-2
// prefetched from L2-hot inbf; bacc written without atomics.
__global__ __launch_bounds__(256) void sweep_kernel(const float* __restrict__ w,
                                                    const float* __restrict__ bias,
                                                    const unsigned int* __restrict__ table,
                                                    const unsigned char* __restrict__ flags,
                                                    const unsigned short* __restrict__ inbf,
                                                    float* __restrict__ partial) {
    __shared__ unsigned short lw[32][264];   // 32 classes x 256 K bf16 (16.9 KB)
    __shared__ unsigned int lmask[32][32];   // 4-bit counts per class x 256 b (4 KB)
    __shared__ float cs[32];                 // bias[c] - log(ec(c))
    __shared__ float sf[32];                 // 1.0 iff c in sampled set
    __shared__ float bacc[BATCH];

    const int tid  = threadIdx.x;
    const int lane = tid & 63;
    const int wv   = tid >> 6;
    const int m    = lane & 15;
    const int quad = lane >> 4;

    // B-fragments for tt=0 (global, L2-hot; independent of LDS staging)
    const unsigned short* bbase = inbf + (wv * 64 + m) * DIM + quad * 8;
    bf16x8 bfc[8], bfn[8];
    #pragma unroll
    for (int kk = 0; kk < 8; ++kk) bfc[kk] = *(const bf16x8*)(bbase + kk * 32);

    #pragma unroll 1
    for (int p = 0; p < 2; ++p) {
        const int c0 = blockIdx.x * 64 + p * 32;

        // ---- stage A: 32 rows x 1 KB fp32, fully coalesced, convert to bf16 ----
        #pragma unroll
        for (int k = 0; k < 8; ++k) {
            const int lrow = (tid >> 6) + k * 4;          // 0..31
            const int col  = (tid & 63) * 4;              // 0..252
            int frow = c0 + lrow;
            frow = frow < NUM_CLASSES ? frow : NUM_CLASSES - 1;  // clamp pad rows
            float4 v = *(const float4*)(w + (size_t)frow * DIM + col);
            ushort4 pk;
            pk.x = f2bf(v.x); pk.y = f2bf(v.y); pk.z = f2bf(v.z); pk.w = f2bf(v.w);
            *(ushort4*)(&lw[lrow][col]) = pk;
        }
        // ---- stage masks: 1024 words coalesced (table padded+zeroed past 100k) ----
        ((int4*)&lmask[0][0])[tid] = ((const int4*)(table + (size_t)c0 * 32))[tid];
        if (tid < 32) {
            const int c = c0 + tid;
            const int cc = c < NUM_CLASSES ? c : NUM_CLASSES - 1;
            cs[tid] = bias[cc] + neg_log_ec_fast(c);
            sf[tid] = flags[c] ? 1.0f : 0.0f;             // pad classes: kf=0,sf=0
        }
        __syncthreads();

        // A-fragments for this wave: 32 classes x full K, register-cached
        bf16x8 af[2][8];
        #pragma unroll
        for (int s = 0; s < 2; ++s)
            #pragma unroll
            for (int kk = 0; kk < 8; ++kk)
                af[s][kk] = *(const bf16x8*)(&lw[s * 16 + m][kk * 32 + quad * 8]);

        #pragma unroll
        for (int tt = 0; tt < 4; ++tt) {
            // depth-2 prefetch of next batch-tile's B-frags
            {
                const unsigned short* bp = bbase + (((tt + 1) & 3) * 16) * DIM;
                #pragma unroll
                for (int kk = 0; kk < 8; ++kk) bfn[kk] = *(const bf16x8*)(bp + kk * 32);
            }
            f32x4 a0 = {0, 0, 0, 0}, a1 = {0, 0, 0, 0};
            #pragma unroll
            for (int kk = 0; kk < 8; ++kk) {
                a0 = __builtin_amdgcn_mfma_f32_16x16x32_bf16(af[0][kk], bfc[kk], a0, 0, 0, 0);
                a1 = __builtin_amdgcn_mfma_f32_16x16x32_bf16(af[1][kk], bfc[kk], a1, 0, 0, 0);
            }
            // epilogue: C/D row(class)=quad*4+r, col(batch)=m
            const int widx = wv * 8 + tt * 2 + (m >> 3);
            const int nsh  = (m & 7) * 4;
            float ps = 0.0f;
            #pragma unroll
            for (int r = 0; r < 4; ++r) {
                {
                    const int cl = quad * 4 + r;
                    float l = a0[r] + cs[cl];
                    float kf = (float)((lmask[cl][widx] >> nsh) & 15u);
                    float base = fmaxf(l, 0.0f) + __logf(1.0f + __expf(-fabsf(l)));
                    ps += (kf + sf[cl]) * base - kf * l * (1.0f / (float)NUM_TRUE);
                }
                {
                    const int cl = 16 + quad * 4 + r;
                    float l = a1[r] + cs[cl];
                    float kf = (float)((lmask[cl][widx] >> nsh) & 15u);
                    float base = fmaxf(l, 0.0f) + __logf(1.0f + __expf(-fabsf(l)));
                    ps += (kf + sf[cl]) * base - kf * l * (1.0f / (float)NUM_TRUE);
                }
            }
            ps += __shfl_xor(ps, 16); ps += __shfl_xor(ps, 32);  // sum quads
            if (quad == 0) {
                const int bi = wv * 64 + tt * 16 + m;            // unique per block
                if (p == 0) bacc[bi] = ps; else bacc[bi] += ps;
            }
            #pragma unroll
            for (int kk = 0; kk < 8; ++kk) bfc[kk] = bfn[kk];
        }
        __syncthreads();
    }
    partial[(size_t)blockIdx.x * BATCH + tid] = bacc[tid];
}

// ---- final reduce: out[b] = sum over 1563 block partials ----
__global__ __launch_bounds__(256) void reduce_kernel(const float* __restrict__ partial,
                                                     float* __restrict__ out) {
    __shared__ float wsum[4];
    const int b = blockIdx.x;
    const int tid = threadIdx.x;
    float v = 0.0f;
    for (int j = tid; j < SWEEP_BLOCKS; j += 256)
        v += partial[(size_t)j * BATCH + b];
    v += __shfl_xor(v, 1);  v += __shfl_xor(v, 2);  v += __shfl_xor(v, 4);
    v += __shfl_xor(v, 8);  v += __shfl_xor(v, 16); v += __shfl_xor(v, 32);
    if ((tid & 63) == 0) wsum[tid >> 6] = v;
    __syncthreads();
    if (tid == 0) out[b] = wsum[0] + wsum[1] + wsum[2] + wsum[3];
}

extern "C" void kernel_launch(void* const* d_in, const int* in_sizes, int n_in,
                              void* d_out, int out_size, void* d_ws, size_t ws_size,
                              hipStream_t stream) {
    const float* inputs  = (const float*)d_in[0];   // [256,256]
    const float* w       = (const float*)d_in[1];   // [100000,256]
    const float* bias    = (const float*)d_in[2];   // [100000]
    const int*   labels  = (const int*)d_in[3];     // [256,1024]
    const int*   sampled = (const int*)d_in[4];     // [16384]
    float* out = (float*)d_out;                     // [256]

    // table padded to 100032 classes so the last sweep block reads zeros
    unsigned int*   table   = (unsigned int*)d_ws;                        // 12,804,096 B
    unsigned char*  flags   = (unsigned char*)d_ws + 12804096;            // 100,032 B
    unsigned short* inbf    = (unsigned short*)((char*)d_ws + 12904128);  // 131,072 B
    float*          partial = (float*)((char*)d_ws + 13035200);           // 1,600,512 B

    hipMemsetAsync(d_ws, 0, 12904128, stream);      // table + flags
    scatter_kernel<<<(BATCH * NUM_TRUE) / 256, 256, 0, stream>>>(labels, sampled, inputs,
                                                                 table, flags, inbf);
    sweep_kernel<<<SWEEP_BLOCKS, 256, 0, stream>>>(w, bias, table, flags, inbf, partial);
    reduce_kernel<<<BATCH, 256, 0, stream>>>(partial, out);
}